// Round 8
// baseline (422.234 us; speedup 1.0000x reference)
//
#include <hip/hip_runtime.h>

// LSTM scan, B=8192 chains, T=2048 steps, D=H=2. 8 lanes/element (r6
// layout, proven absmax 0.00195). Round 8: TWO independent elements per
// thread, per-step interleaved (ILP2). Rationale: wall is pinned at
// ~218 cyc/step by 4 dependent transcendentals (tau ~50 cyc each) on the
// serial chain; with 1 wave/SIMD nothing fills the stalls. A second
// in-thread chain issues during the first chain's trans latency:
// pair-wall ~ max(chain 218, 2*issue ~222) -> ~112 cyc/elem-step.
// Also: HSEL+cndmask fused into one bank-masked DPP merge.
//
// Lanes (q=tid&7): l0:i0 l1:i1 l2:f0 l3:f1 l4:o1 l5:o0 l6:g1 l7:g0
// mirror pairs (0,7)(1,6)(2,5)(3,4) = i<->g, f<->o.
// col(q) = (q&1)^((q>>2)&1). h lands at l2,l3 (quad0) / l5,l4 (quad1).

#define LOG2E 1.4426950408889634f

template <int CTRL>
__device__ __forceinline__ float qdpp(float v) {
    int i = __builtin_bit_cast(int, v);
    i = __builtin_amdgcn_update_dpp(0, i, CTRL, 0xF, 0xF, true);
    return __builtin_bit_cast(float, i);
}
// masked merge DPP: banks outside BANK mask keep `old`
template <int CTRL, int BANK>
__device__ __forceinline__ float mdpp(float old, float v) {
    int i = __builtin_amdgcn_update_dpp(__builtin_bit_cast(int, old),
                                        __builtin_bit_cast(int, v),
                                        CTRL, 0xF, BANK, false);
    return __builtin_bit_cast(float, i);
}
#define DPP_HSEL    0x14   // quad_perm(0,1,1,0)
#define DPP_BCAST2  0xAA   // quad_perm(2,2,2,2)
#define DPP_BCAST3  0xFF   // quad_perm(3,3,3,3)
#define DPP_SWAP2   0x4E   // quad_perm(2,3,0,1)
#define DPP_MIRROR8 0x141  // row_half_mirror

__global__ __launch_bounds__(64, 1) void lstm_oct_ilp2_kernel(
    const float* __restrict__ x,
    const float* __restrict__ h0,
    const float* __restrict__ c0,
    const float* __restrict__ w_ih,
    const float* __restrict__ w_hh,
    const float* __restrict__ b_ih,
    const float* __restrict__ b_hh,
    float* __restrict__ out,
    int B, int T)
{
    const int tid = blockIdx.x * blockDim.x + threadIdx.x;
    const int pp = tid >> 3;       // element-pair index
    const int q  = tid & 7;        // lane within octet
    if (pp >= B / 2) return;
    const int e0 = 2 * pp;
    const int e1 = 2 * pp + 1;

    const int r = (q < 4) ? q : 11 - q;   // gate row (i0,i1,f0,f1,g0,g1,o0,o1)
    const bool isTanh = (q >= 6);
    const bool sel45  = (q == 4) || (q == 5);
    const bool selMid = (q >= 2) && (q <= 5);
    const int col = (q & 1) ^ ((q >> 2) & 1);

    // exp2 arg scale prefolded: sigma -log2e, tanh +2*log2e; tanh lanes
    // emit 2L*tanh(g) via (m,d) = (-4L, 2L). c carried scaled by 2L.
    const float a = isTanh ? (2.0f * LOG2E) : (-LOG2E);
    const float m = isTanh ? (-4.0f * LOG2E) : 1.0f;
    const float d = isTanh ? (2.0f * LOG2E) : 0.0f;

    const float wi0 = w_ih[2 * r] * a, wi1 = w_ih[2 * r + 1] * a;
    const float wh0 = w_hh[2 * r] * a, wh1 = w_hh[2 * r + 1] * a;
    const float bias = (b_ih[r] + b_hh[r]) * a;

    float hU = h0[2 * e0 + col], cU = c0[2 * e0 + col] * (2.0f * LOG2E);
    float hV = h0[2 * e1 + col], cV = c0[2 * e1 + col] * (2.0f * LOG2E);

    const int NI = T >> 1;  // float4s per row (2 timesteps each)
    const float4* __restrict__ xpU =
        reinterpret_cast<const float4*>(x) + (size_t)e0 * NI;
    const float4* __restrict__ xpV =
        reinterpret_cast<const float4*>(x) + (size_t)e1 * NI;

    auto step = [&](float& h, float& cs, float x0, float x1) {
        // quad1 locals 2,3 <- (h0,h1) from locals 1,0; quad0 keeps h
        float hs  = mdpp<DPP_HSEL, 0xA>(h, h);
        float hh0 = qdpp<DPP_BCAST2>(hs);
        float hh1 = qdpp<DPP_BCAST3>(hs);
        float ax = fmaf(wi1, x1, fmaf(wi0, x0, bias));      // off-chain
        float g  = fmaf(wh1, hh1, fmaf(wh0, hh0, ax));
        float n  = fmaf(m, __builtin_amdgcn_rcpf(1.0f + __builtin_amdgcn_exp2f(g)), d);
        float mv = qdpp<DPP_MIRROR8>(n);
        float X = sel45  ? mv : n;
        float Y = selMid ? cs : mv;
        float p = X * Y;                    // sigma_i*t'g | sigma_f*c'
        float ps = qdpp<DPP_SWAP2>(p);
        cs = p + ps;                        // scaled c, all lanes
        float tc = fmaf(-2.0f, __builtin_amdgcn_rcpf(1.0f + __builtin_amdgcn_exp2f(cs)), 1.0f);
        float Z = sel45 ? n : mv;           // sigma_o at locals 2,3 / 0,1
        h = Z * tc;
    };

    constexpr int BV = 4;   // float4s per buffer per chain = 8 timesteps
    float4 AU[BV], AV[BV], BU[BV], BVv[BV];

    auto loadU = [&](float4* buf, int batch) {
#pragma unroll
        for (int j = 0; j < BV; ++j) buf[j] = xpU[batch * BV + j];
    };
    auto loadV = [&](float4* buf, int batch) {
#pragma unroll
        for (int j = 0; j < BV; ++j) buf[j] = xpV[batch * BV + j];
    };
    // per-step interleave of the two independent chains
    auto consume = [&](const float4* bu, const float4* bv) {
#pragma unroll
        for (int j = 0; j < BV; ++j) {
            step(hU, cU, bu[j].x, bu[j].y);
            step(hV, cV, bv[j].x, bv[j].y);
            step(hU, cU, bu[j].z, bu[j].w);
            step(hV, cV, bv[j].z, bv[j].w);
        }
    };

    const int nb = NI / BV;
    int bi = 0;
    if (nb >= 2) {
        loadU(AU, 0); loadV(AV, 0);
        loadU(BU, 1); loadV(BVv, 1);
        for (bi = 0; bi + 1 < nb; bi += 2) {
            consume(AU, AV);
            if (bi + 2 < nb) { loadU(AU, bi + 2); loadV(AV, bi + 2); }
            consume(BU, BVv);
            if (bi + 3 < nb) { loadU(BU, bi + 3); loadV(BVv, bi + 3); }
        }
        if (bi < nb) { consume(AU, AV); ++bi; }
    }
    for (int i = bi * BV; i < NI; ++i) {    // tail (empty for T=2048)
        float4 u = xpU[i], v = xpV[i];
        step(hU, cU, u.x, u.y);
        step(hV, cV, v.x, v.y);
        step(hU, cU, u.z, u.w);
        step(hV, cV, v.z, v.w);
    }

    // cs = 2L*c -> c = cs * ln2/2 ; l0 holds col0, l1 holds col1
    if (q < 2) {
        out[2 * e0 + q] = cU * (0.5f / LOG2E);
        out[2 * e1 + q] = cV * (0.5f / LOG2E);
    }
}

extern "C" void kernel_launch(void* const* d_in, const int* in_sizes, int n_in,
                              void* d_out, int out_size, void* d_ws, size_t ws_size,
                              hipStream_t stream) {
    const float* x    = (const float*)d_in[0];
    const float* h0   = (const float*)d_in[1];
    const float* c0   = (const float*)d_in[2];
    const float* w_ih = (const float*)d_in[3];
    const float* w_hh = (const float*)d_in[4];
    const float* b_ih = (const float*)d_in[5];
    const float* b_hh = (const float*)d_in[6];
    float* out = (float*)d_out;

    const int B = in_sizes[1] / 2;           // h0 is (B, H=2)
    const int T = in_sizes[0] / (B * 2);     // x is (B, T, D=2)

    const int threads = (B / 2) * 8;         // 8 lanes per element pair
    dim3 block(64);
    dim3 grid((threads + 63) / 64);
    hipLaunchKernelGGL(lstm_oct_ilp2_kernel, grid, block, 0, stream,
                       x, h0, c0, w_ih, w_hh, b_ih, b_hh, out, B, T);
}

// Round 9
// 333.949 us; speedup vs baseline: 1.2644x; 1.2644x over previous
//
#include <hip/hip_runtime.h>

// LSTM scan, B=8192 chains, T=2048 steps, D=H=2. 8 lanes/element (r6
// layout, proven). Round 9: Pade(5,4) rational nonlinearities — ONE rcp
// per nonlinearity instead of exp2->rcp (two dependent trans). Chain has
// 2 trans instead of 4. Issue grows (+~12 ops) but 8-lane has ~100 cyc
// issue slack, so wall should drop toward ~175-190 cyc/step.
// Math identical to r4 (Pade everywhere), which measured absmax 0.0156.
//
// Lanes (q=tid&7): l0:i0 l1:i1 l2:f0 l3:f1 l4:o1 l5:o0 l6:g1 l7:g0
// mirror pairs (0,7)(1,6)(2,5)(3,4) = i<->g, f<->o.
// col(q) = (q&1)^((q>>2)&1). h lands at l2,l3 (quad0) / l5,l4 (quad1).
// sigma(x) = 0.5 + 0.5*tanh(x/2): 0.5 arg-scale folded into weights,
// affine folded into the per-lane fma(m,t,d) slot.

template <int CTRL>
__device__ __forceinline__ float qdpp(float v) {
    int i = __builtin_bit_cast(int, v);
    i = __builtin_amdgcn_update_dpp(0, i, CTRL, 0xF, 0xF, true);
    return __builtin_bit_cast(float, i);
}
// masked merge DPP: banks outside BANK mask keep `old`
template <int CTRL, int BANK>
__device__ __forceinline__ float mdpp(float old, float v) {
    int i = __builtin_amdgcn_update_dpp(__builtin_bit_cast(int, old),
                                        __builtin_bit_cast(int, v),
                                        CTRL, 0xF, BANK, false);
    return __builtin_bit_cast(float, i);
}
#define DPP_HSEL    0x14   // quad_perm(0,1,1,0)
#define DPP_BCAST2  0xAA   // quad_perm(2,2,2,2)
#define DPP_BCAST3  0xFF   // quad_perm(3,3,3,3)
#define DPP_SWAP2   0x4E   // quad_perm(2,3,0,1)
#define DPP_MIRROR8 0x141  // row_half_mirror

// tanh(x) ~= x*(x^4+105x^2+945)/(15x^4+420x^2+945), clamped to [-1,1].
// |err| <= ~4e-4 for |x|<3.8; clamp exact beyond (r4-proven accuracy).
__device__ __forceinline__ float tanh_pade(float x) {
    float x2 = x * x;
    float num = fmaf(x2 + 105.0f, x2, 945.0f) * x;
    float den = fmaf(fmaf(x2, 15.0f, 420.0f), x2, 945.0f);
    float t = num * __builtin_amdgcn_rcpf(den);
    return fminf(fmaxf(t, -1.0f), 1.0f);
}

__global__ __launch_bounds__(64, 1) void lstm_oct_pade_kernel(
    const float* __restrict__ x,
    const float* __restrict__ h0,
    const float* __restrict__ c0,
    const float* __restrict__ w_ih,
    const float* __restrict__ w_hh,
    const float* __restrict__ b_ih,
    const float* __restrict__ b_hh,
    float* __restrict__ out,
    int B, int T)
{
    const int tid = blockIdx.x * blockDim.x + threadIdx.x;
    const int e = tid >> 3;        // batch element
    const int q = tid & 7;         // lane within octet
    if (e >= B) return;

    const int r = (q < 4) ? q : 11 - q;   // gate row (i0,i1,f0,f1,g0,g1,o0,o1)
    const bool isTanh = (q >= 6);
    const bool sel45  = (q == 4) || (q == 5);
    const bool selMid = (q >= 2) && (q <= 5);
    const int col = (q & 1) ^ ((q >> 2) & 1);

    // sigma lanes: arg scale 0.5 (folded), n = 0.5*t + 0.5
    // tanh  lanes: arg scale 1,            n = t
    const float a = isTanh ? 1.0f : 0.5f;
    const float m = isTanh ? 1.0f : 0.5f;
    const float d = isTanh ? 0.0f : 0.5f;

    const float wi0 = w_ih[2 * r] * a, wi1 = w_ih[2 * r + 1] * a;
    const float wh0 = w_hh[2 * r] * a, wh1 = w_hh[2 * r + 1] * a;
    const float bias = (b_ih[r] + b_hh[r]) * a;

    float h  = h0[2 * e + col];
    float cs = c0[2 * e + col];    // plain (unscaled) cell state

    const int NI = T >> 1;  // float4s per element row (2 timesteps each)
    const float4* __restrict__ xp =
        reinterpret_cast<const float4*>(x) + (size_t)e * NI;

    auto step = [&](float x0, float x1) {
        // quad1 locals 2,3 <- (h0,h1) from locals 1,0; quad0 keeps h
        float hs  = mdpp<DPP_HSEL, 0xA>(h, h);
        float hh0 = qdpp<DPP_BCAST2>(hs);
        float hh1 = qdpp<DPP_BCAST3>(hs);
        float ax = fmaf(wi1, x1, fmaf(wi0, x0, bias));   // off-chain
        float g  = fmaf(wh1, hh1, fmaf(wh0, hh0, ax));
        float n  = fmaf(m, tanh_pade(g), d);   // sigma(.)|tanh(.) per lane
        float mv = qdpp<DPP_MIRROR8>(n);
        float X = sel45  ? mv : n;             // sigma_i | sigma_f side
        float Y = selMid ? cs : mv;            // c | partner nonlin
        float p = X * Y;                       // sigma_i*tg | sigma_f*c
        float ps = qdpp<DPP_SWAP2>(p);
        cs = p + ps;                           // c' for this lane's col
        float tc = tanh_pade(cs);
        float Z = sel45 ? n : mv;              // sigma_o at locals 2,3 / 0,1
        h = Z * tc;
    };

    constexpr int BV = 8;              // float4s per buffer = 16 timesteps
    float4 A[BV], Bb[BV];

    auto loadbuf = [&](float4* buf, int batch) {
#pragma unroll
        for (int j = 0; j < BV; ++j) buf[j] = xp[batch * BV + j];
    };
    auto consume = [&](const float4* buf) {
#pragma unroll
        for (int j = 0; j < BV; ++j) {
            step(buf[j].x, buf[j].y);
            step(buf[j].z, buf[j].w);
        }
    };

    const int nb = NI / BV;
    int bi = 0;
    if (nb >= 2) {
        loadbuf(A, 0);
        loadbuf(Bb, 1);
        for (bi = 0; bi + 1 < nb; bi += 2) {
            consume(A);
            if (bi + 2 < nb) loadbuf(A, bi + 2);
            consume(Bb);
            if (bi + 3 < nb) loadbuf(Bb, bi + 3);
        }
        if (bi < nb) { consume(A); ++bi; }
    }
    for (int i = bi * BV; i < NI; ++i) {   // tail (empty for T=2048)
        float4 v = xp[i];
        step(v.x, v.y);
        step(v.z, v.w);
    }

    if (q < 2) out[2 * e + q] = cs;    // l0: col0, l1: col1
}

extern "C" void kernel_launch(void* const* d_in, const int* in_sizes, int n_in,
                              void* d_out, int out_size, void* d_ws, size_t ws_size,
                              hipStream_t stream) {
    const float* x    = (const float*)d_in[0];
    const float* h0   = (const float*)d_in[1];
    const float* c0   = (const float*)d_in[2];
    const float* w_ih = (const float*)d_in[3];
    const float* w_hh = (const float*)d_in[4];
    const float* b_ih = (const float*)d_in[5];
    const float* b_hh = (const float*)d_in[6];
    float* out = (float*)d_out;

    const int B = in_sizes[1] / 2;           // h0 is (B, H=2)
    const int T = in_sizes[0] / (B * 2);     // x is (B, T, D=2)

    const int threads = B * 8;               // 8 lanes per element
    dim3 block(64);
    dim3 grid((threads + 63) / 64);
    hipLaunchKernelGGL(lstm_oct_pade_kernel, grid, block, 0, stream,
                       x, h0, c0, w_ih, w_hh, b_ih, b_hh, out, B, T);
}